// Round 8
// baseline (197.708 us; speedup 1.0000x reference)
//
#include <hip/hip_runtime.h>
#include <math.h>

#define NT 262144
#define KD 512
#define NE 64
#define DE 64

constexpr int BM = 128;       // tokens per block
constexpr int LA = 132;       // LDS stride for h_norm [d][tok]
constexpr int NS = KD / 32;   // 16 K-steps
constexpr int WS_EN = 49152;  // u32 offset of e_norm^T region in workspace

using f32x4 = __attribute__((ext_vector_type(4))) float;
using s16x8 = __attribute__((ext_vector_type(8))) short;

typedef const __attribute__((address_space(1))) unsigned int* gp1_t;
typedef __attribute__((address_space(3))) unsigned int* lp3_t;

// ---- 3-term truncated bf16 split of fp32: x = x1 + x2 + x3, |res| <= 2^-24|x| ----
__device__ __forceinline__ void split8(float4 lo, float4 hi,
                                       s16x8& o1, s16x8& o2, s16x8& o3) {
    float x[8] = {lo.x, lo.y, lo.z, lo.w, hi.x, hi.y, hi.z, hi.w};
    union { unsigned int u[4]; s16x8 v; } r1, r2, r3;
    #pragma unroll
    for (int p = 0; p < 4; ++p) {
        float f0 = x[2 * p], f1 = x[2 * p + 1];
        unsigned int a = __float_as_uint(f0), b = __float_as_uint(f1);
        unsigned int a1 = a & 0xFFFF0000u, b1 = b & 0xFFFF0000u;
        r1.u[p] = (a1 >> 16) | b1;
        float q0 = f0 - __uint_as_float(a1);
        float q1 = f1 - __uint_as_float(b1);
        unsigned int a2 = __float_as_uint(q0) & 0xFFFF0000u;
        unsigned int b2 = __float_as_uint(q1) & 0xFFFF0000u;
        r2.u[p] = (a2 >> 16) | b2;
        float s0 = q0 - __uint_as_float(a2);
        float s1 = q1 - __uint_as_float(b2);
        r3.u[p] = (__float_as_uint(s0) >> 16) | (__float_as_uint(s1) & 0xFFFF0000u);
    }
    o1 = r1.v; o2 = r2.v; o3 = r3.v;
}

__device__ __forceinline__ s16x8 ld_frag(const unsigned int* p) {
    union { uint4 q; s16x8 v; } u;
    u.q = *(const uint4*)p;
    return u.v;
}

// ---- prep: blocks 0..15 split W into FRAGMENT-ORDER bf16 planes;
//      block 16 writes e_norm^T fp32.
// W region layout (u32): group g = ks*4 + ct (64 groups); within a group,
// 3 planes x 64 lanes x 4 u32 (768 u32 = 3KB). One K-step = 4 groups = 12KB
// contiguous -- exactly what the main kernel DMA-stages per step.
__global__ void prep(const float* __restrict__ W, const float* __restrict__ E,
                     unsigned int* __restrict__ ws) {
    const int tid = threadIdx.x;
    if (blockIdx.x < 16) {
        const int idx = blockIdx.x * 256 + tid;     // chunk: row*64 + k8
        const int row = idx >> 6, k8 = idx & 63;
        const float* src = W + (size_t)row * KD + k8 * 8;
        float4 lo = *(const float4*)src, hi = *(const float4*)(src + 4);
        s16x8 o1, o2, o3;
        split8(lo, hi, o1, o2, o3);
        union { s16x8 v; uint4 q; } u1, u2, u3;
        u1.v = o1; u2.v = o2; u3.v = o3;
        const int ks = k8 >> 2, lk = k8 & 3, ct = row >> 4, lr = row & 15;
        const int g = ks * 4 + ct, lane = lk * 16 + lr;
        unsigned int* base = ws + (size_t)g * 768 + lane * 4;
        *(uint4*)(base)       = u1.q;
        *(uint4*)(base + 256) = u2.q;
        *(uint4*)(base + 512) = u3.q;
    } else {
        float* en = (float*)(ws + WS_EN);
        const int er = tid >> 2, part = tid & 3;
        float ss = 0.f;
        float4 ev[4];
        #pragma unroll
        for (int u = 0; u < 4; ++u) {
            ev[u] = *(const float4*)(E + er * DE + part * 16 + u * 4);
            ss = fmaf(ev[u].x, ev[u].x, ss);
            ss = fmaf(ev[u].y, ev[u].y, ss);
            ss = fmaf(ev[u].z, ev[u].z, ss);
            ss = fmaf(ev[u].w, ev[u].w, ss);
        }
        ss += __shfl_xor(ss, 1, 64);
        ss += __shfl_xor(ss, 2, 64);
        const float inv_e = 1.0f / fmaxf(sqrtf(ss), 1e-12f);
        #pragma unroll
        for (int u = 0; u < 4; ++u) {
            int d = part * 16 + u * 4;
            en[(d + 0) * 64 + er] = ev[u].x * inv_e;
            en[(d + 1) * 64 + er] = ev[u].y * inv_e;
            en[(d + 2) * 64 + er] = ev[u].z * inv_e;
            en[(d + 3) * 64 + er] = ev[u].w * inv_e;
        }
    }
}

// ---- fused main ----
// A-operand: direct global->VGPR, TWO-step register pipeline (X/Y buffers,
// ~1200cy of cover for the ~900cy HBM latency; viable now that B left the
// register path -- VGPR was 52 with 76 headroom at 4 blk/CU).
// B-operand: 12KB/step staged once per block via global_load_lds, double
// buffered, with COUNTED vmcnt(4): at the top of step k the per-wave
// outstanding VMEM queue is [A(k):4 oldest, B(k):3, A(k+1):4]; vmcnt(4)
// retires exactly A(k)+B(k) and leaves A(k+1) in flight. sched_barrier(0)
// after the B-issue pins the B-before-A order the count depends on.
// LDS: 24KB B dbuf, overlaid by 33KB h_norm -> 4 blocks/CU.
__global__ __launch_bounds__(256, 4) void moe_all(const float* __restrict__ h,
                                                  const unsigned int* __restrict__ wsW,
                                                  const float* __restrict__ enorm,
                                                  const float* __restrict__ tau_p,
                                                  float* __restrict__ out) {
    __shared__ float smem[DE * LA];   // [0,6144): B dbuf; then h_norm overlay

    const int tid = threadIdx.x;
    const int lane = tid & 63;
    const int wv = tid >> 6;          // wave 0..3 -> tokens [wv*32, wv*32+32)
    const int lr = lane & 15;         // fragment row/col within 16
    const int lk = lane >> 4;         // k-group 0..3
    const long tok0 = (long)blockIdx.x * BM;
    const long wtok = tok0 + wv * 32;

    f32x4 acc[2][4];                  // [row-tile][col-tile], 16x16 each
    #pragma unroll
    for (int rt = 0; rt < 2; ++rt)
        #pragma unroll
        for (int ct = 0; ct < 4; ++ct)
            acc[rt][ct] = (f32x4){0.f, 0.f, 0.f, 0.f};

    // B: whole block cooperatively copies step KS's 12KB (linear, lane*16B)
#define STAGE_B(CUR, KS)                                                       \
    {                                                                          \
        _Pragma("unroll")                                                      \
        for (int i = 0; i < 3; ++i) {                                          \
            const unsigned int* g = wsW + (size_t)(KS) * 3072 + i * 1024       \
                                    + wv * 256 + lane * 4;                     \
            float* l = smem + (CUR) * 3072 + i * 1024 + wv * 256;              \
            __builtin_amdgcn_global_load_lds((gp1_t)(const void*)g,            \
                                             (lp3_t)(void*)l, 16, 0, 0);       \
        }                                                                      \
    }

    // One K-step. LASTVM: drain fully (final step). DO_B/DO_A: stage B[KS+1] /
    // load A[KS+2] into this phase's register buffer (consumed 2 steps later).
#define PHASE(AL0, AH0, AL1, AH1, KS, LASTVM, DO_B, DO_A)                      \
    {                                                                          \
        if (LASTVM) { asm volatile("s_waitcnt vmcnt(0)" ::: "memory"); }       \
        else        { asm volatile("s_waitcnt vmcnt(4)" ::: "memory"); }       \
        __builtin_amdgcn_s_barrier();                                          \
        if (DO_B) { STAGE_B(((KS) + 1) & 1, (KS) + 1); }                       \
        __builtin_amdgcn_sched_barrier(0);                                     \
        s16x8 a1[2], a2[2], a3[2];                                             \
        split8(AL0, AH0, a1[0], a2[0], a3[0]);                                 \
        split8(AL1, AH1, a1[1], a2[1], a3[1]);                                 \
        if (DO_A) {                                                            \
            const int o = ((KS) + 2) * 32;                                     \
            AL0 = *(const float4*)(pa0 + o); AH0 = *(const float4*)(pa0 + o + 4); \
            AL1 = *(const float4*)(pa1 + o); AH1 = *(const float4*)(pa1 + o + 4); \
        }                                                                      \
        const float* bbase = smem + ((KS) & 1) * 3072;                         \
        _Pragma("unroll")                                                      \
        for (int ct = 0; ct < 4; ++ct) {                                       \
            const unsigned int* bb =                                           \
                (const unsigned int*)(bbase + ct * 768) + lane * 4;            \
            s16x8 b1 = ld_frag(bb);                                            \
            s16x8 b2 = ld_frag(bb + 256);                                      \
            s16x8 b3 = ld_frag(bb + 512);                                      \
            f32x4 c0 = acc[0][ct], c1 = acc[1][ct];                            \
            c0 = __builtin_amdgcn_mfma_f32_16x16x32_bf16(a1[0], b1, c0, 0, 0, 0); \
            c1 = __builtin_amdgcn_mfma_f32_16x16x32_bf16(a1[1], b1, c1, 0, 0, 0); \
            c0 = __builtin_amdgcn_mfma_f32_16x16x32_bf16(a2[0], b1, c0, 0, 0, 0); \
            c1 = __builtin_amdgcn_mfma_f32_16x16x32_bf16(a2[1], b1, c1, 0, 0, 0); \
            c0 = __builtin_amdgcn_mfma_f32_16x16x32_bf16(a1[0], b2, c0, 0, 0, 0); \
            c1 = __builtin_amdgcn_mfma_f32_16x16x32_bf16(a1[1], b2, c1, 0, 0, 0); \
            c0 = __builtin_amdgcn_mfma_f32_16x16x32_bf16(a3[0], b1, c0, 0, 0, 0); \
            c1 = __builtin_amdgcn_mfma_f32_16x16x32_bf16(a3[1], b1, c1, 0, 0, 0); \
            c0 = __builtin_amdgcn_mfma_f32_16x16x32_bf16(a2[0], b2, c0, 0, 0, 0); \
            c1 = __builtin_amdgcn_mfma_f32_16x16x32_bf16(a2[1], b2, c1, 0, 0, 0); \
            c0 = __builtin_amdgcn_mfma_f32_16x16x32_bf16(a1[0], b3, c0, 0, 0, 0); \
            c1 = __builtin_amdgcn_mfma_f32_16x16x32_bf16(a1[1], b3, c1, 0, 0, 0); \
            acc[0][ct] = c0; acc[1][ct] = c1;                                  \
        }                                                                      \
    }

    // A base pointers: lane reads h[wtok + {0,16} + lr][k..k+8)
    const float* pa0 = h + (wtok + 0 * 16 + lr) * (long)KD + lk * 8;
    const float* pa1 = h + (wtok + 1 * 16 + lr) * (long)KD + lk * 8;

    // prologue: B[0] DMA first (oldest in vmcnt queue), then A[0], A[1] regs
    STAGE_B(0, 0);
    __builtin_amdgcn_sched_barrier(0);
    float4 xl0 = *(const float4*)(pa0),      xh0 = *(const float4*)(pa0 + 4);
    float4 xl1 = *(const float4*)(pa1),      xh1 = *(const float4*)(pa1 + 4);
    float4 yl0 = *(const float4*)(pa0 + 32), yh0 = *(const float4*)(pa0 + 36);
    float4 yl1 = *(const float4*)(pa1 + 32), yh1 = *(const float4*)(pa1 + 36);

    for (int ks = 0; ks < NS - 2; ks += 2) {
        PHASE(xl0, xh0, xl1, xh1, ks,     0, 1, 1);
        PHASE(yl0, yh0, yl1, yh1, ks + 1, 0, 1, 1);
    }
    PHASE(xl0, xh0, xl1, xh1, NS - 2, 0, 1, 0);   // stages B[15], no A-load
    PHASE(yl0, yh0, yl1, yh1, NS - 1, 1, 0, 0);   // final: full drain

    // ---- per-token L2 norm from fragments ----
    // C/D layout: col = lane&15 (d), row = (lane>>4)*4 + reg (token within 16)
    float inv_n[2][4];
    #pragma unroll
    for (int rt = 0; rt < 2; ++rt) {
        #pragma unroll
        for (int r = 0; r < 4; ++r) {
            float ss = 0.f;
            #pragma unroll
            for (int ct = 0; ct < 4; ++ct)
                ss = fmaf(acc[rt][ct][r], acc[rt][ct][r], ss);
            ss += __shfl_xor(ss, 1, 64);
            ss += __shfl_xor(ss, 2, 64);
            ss += __shfl_xor(ss, 4, 64);
            ss += __shfl_xor(ss, 8, 64);
            inv_n[rt][r] = 1.0f / fmaxf(sqrtf(ss), 1e-12f);
        }
    }

    __syncthreads();   // all stage-1 LDS traffic done (h_norm overlays it)

    // h_norm -> smem as [d][tok]
    #pragma unroll
    for (int rt = 0; rt < 2; ++rt)
        #pragma unroll
        for (int ct = 0; ct < 4; ++ct)
            #pragma unroll
            for (int r = 0; r < 4; ++r) {
                const int d = ct * 16 + lr;
                const int t = wv * 32 + rt * 16 + lk * 4 + r;
                smem[d * LA + t] = acc[rt][ct][r] * inv_n[rt][r];
            }
    __syncthreads();   // h_norm visible to all

    // ---- stage 2: scores[128][64] = h_norm @ e_norm^T (K=64), fp32 VALU ----
    const int tx = tid & 15;   // cols tx*4 + j
    const int ty = tid >> 4;   // tokens p*64 + ty*4 + i
    float sacc[2][4][4];
    #pragma unroll
    for (int p = 0; p < 2; ++p)
        #pragma unroll
        for (int i = 0; i < 4; ++i)
            #pragma unroll
            for (int j = 0; j < 4; ++j) sacc[p][i][j] = 0.0f;

    #pragma unroll 8
    for (int dd = 0; dd < DE; ++dd) {
        const float* ra = smem + dd * LA;
        float4 a0 = *(const float4*)(ra + ty * 4);
        float4 a1v = *(const float4*)(ra + 64 + ty * 4);
        float4 b  = *(const float4*)(enorm + dd * 64 + tx * 4);
        float av[2][4] = {{a0.x, a0.y, a0.z, a0.w}, {a1v.x, a1v.y, a1v.z, a1v.w}};
        float bv[4] = {b.x, b.y, b.z, b.w};
        #pragma unroll
        for (int p = 0; p < 2; ++p)
            #pragma unroll
            for (int i = 0; i < 4; ++i)
                #pragma unroll
                for (int j = 0; j < 4; ++j)
                    sacc[p][i][j] = fmaf(av[p][i], bv[j], sacc[p][i][j]);
    }

    // ---- epilogue: softmax, top-2, outputs ----
    const float inv_tau = 1.0f / tau_p[0];
    float* outS = out;                        // sparse_gates [NT][64]
    float* outI = out + (size_t)NT * 64;      // topk_indices [NT][2] (as float)
    float* outF = out + (size_t)NT * 66;      // full_gates   [NT][64]

    #pragma unroll
    for (int p = 0; p < 2; ++p) {
        #pragma unroll
        for (int i = 0; i < 4; ++i) {
            const long tok = tok0 + p * 64 + ty * 4 + i;
            float s[4];
            #pragma unroll
            for (int j = 0; j < 4; ++j) s[j] = sacc[p][i][j] * inv_tau;

            float m = fmaxf(fmaxf(s[0], s[1]), fmaxf(s[2], s[3]));
            m = fmaxf(m, __shfl_xor(m, 1, 64));
            m = fmaxf(m, __shfl_xor(m, 2, 64));
            m = fmaxf(m, __shfl_xor(m, 4, 64));
            m = fmaxf(m, __shfl_xor(m, 8, 64));

            float g[4], z = 0.f;
            #pragma unroll
            for (int j = 0; j < 4; ++j) { g[j] = __expf(s[j] - m); z += g[j]; }
            z += __shfl_xor(z, 1, 64);
            z += __shfl_xor(z, 2, 64);
            z += __shfl_xor(z, 4, 64);
            z += __shfl_xor(z, 8, 64);
            const float invZ = 1.0f / z;

            *(float4*)(outF + tok * 64 + tx * 4) =
                make_float4(g[0] * invZ, g[1] * invZ, g[2] * invZ, g[3] * invZ);

            // top-2 on s (monotone with gates); ties -> lower index (jax top_k)
            float v1 = -3.4e38f, v2 = -3.4e38f;
            int i1 = 1 << 20, i2 = 1 << 20;
            #pragma unroll
            for (int j = 0; j < 4; ++j) {
                float v = s[j];
                int e = tx * 4 + j;
                if (v > v1 || (v == v1 && e < i1)) { v2 = v1; i2 = i1; v1 = v; i1 = e; }
                else if (v > v2 || (v == v2 && e < i2)) { v2 = v; i2 = e; }
            }
            #pragma unroll
            for (int msk = 1; msk <= 8; msk <<= 1) {
                float o1 = __shfl_xor(v1, msk, 64); int oi1 = __shfl_xor(i1, msk, 64);
                float o2 = __shfl_xor(v2, msk, 64); int oi2 = __shfl_xor(i2, msk, 64);
                if (o1 > v1 || (o1 == v1 && oi1 < i1)) {
                    if (v1 > o2 || (v1 == o2 && i1 < oi2)) { v2 = v1; i2 = i1; }
                    else { v2 = o2; i2 = oi2; }
                    v1 = o1; i1 = oi1;
                } else {
                    if (o1 > v2 || (o1 == v2 && oi1 < i2)) { v2 = o1; i2 = oi1; }
                }
            }

            // softmax over the two top GATE values
            float gv1 = __expf(v1 - m) * invZ;
            float gv2 = __expf(v2 - m) * invZ;
            float qq = __expf(gv2 - gv1);
            float w1 = 1.0f / (1.0f + qq);
            float w2 = qq * w1;

            float sp[4];
            #pragma unroll
            for (int j = 0; j < 4; ++j) {
                int e = tx * 4 + j;
                sp[j] = (e == i1) ? w1 : ((e == i2) ? w2 : 0.0f);
            }
            *(float4*)(outS + tok * 64 + tx * 4) = make_float4(sp[0], sp[1], sp[2], sp[3]);
            if (tx == 0) {
                *(float2*)(outI + tok * 2) = make_float2((float)i1, (float)i2);
            }
        }
    }
#undef STAGE_B
#undef PHASE
}

extern "C" void kernel_launch(void* const* d_in, const int* in_sizes, int n_in,
                              void* d_out, int out_size, void* d_ws, size_t ws_size,
                              hipStream_t stream) {
    const float* h   = (const float*)d_in[0];
    const float* W   = (const float*)d_in[1];
    const float* E   = (const float*)d_in[2];
    const float* tau = (const float*)d_in[3];
    float* out = (float*)d_out;
    unsigned int* ws = (unsigned int*)d_ws;   // 192KB W frags + 16KB e_norm^T

    prep<<<17, 256, 0, stream>>>(W, E, ws);
    moe_all<<<NT / BM, 256, 0, stream>>>(h, ws, (const float*)(ws + WS_EN), tau, out);
}

// Round 9
// 170.227 us; speedup vs baseline: 1.1614x; 1.1614x over previous
//
#include <hip/hip_runtime.h>
#include <math.h>

#define NT 262144
#define KD 512
#define NE 64
#define DE 64

constexpr int BM = 128;       // tokens per block
constexpr int NS = KD / 32;   // 16 K-steps
constexpr int WS_EN = 49152;  // u32 offset of e_norm bf16-split planes
constexpr int LD2 = 68;       // h_norm [tok][d] stride (floats)

using f32x4 = __attribute__((ext_vector_type(4))) float;
using s16x8 = __attribute__((ext_vector_type(8))) short;

typedef const __attribute__((address_space(1))) unsigned int* gp1_t;
typedef __attribute__((address_space(3))) unsigned int* lp3_t;

// ---- 3-term truncated bf16 split of fp32: x = x1 + x2 + x3, |res| <= 2^-24|x| ----
__device__ __forceinline__ void split8(float4 lo, float4 hi,
                                       s16x8& o1, s16x8& o2, s16x8& o3) {
    float x[8] = {lo.x, lo.y, lo.z, lo.w, hi.x, hi.y, hi.z, hi.w};
    union { unsigned int u[4]; s16x8 v; } r1, r2, r3;
    #pragma unroll
    for (int p = 0; p < 4; ++p) {
        float f0 = x[2 * p], f1 = x[2 * p + 1];
        unsigned int a = __float_as_uint(f0), b = __float_as_uint(f1);
        unsigned int a1 = a & 0xFFFF0000u, b1 = b & 0xFFFF0000u;
        r1.u[p] = (a1 >> 16) | b1;
        float q0 = f0 - __uint_as_float(a1);
        float q1 = f1 - __uint_as_float(b1);
        unsigned int a2 = __float_as_uint(q0) & 0xFFFF0000u;
        unsigned int b2 = __float_as_uint(q1) & 0xFFFF0000u;
        r2.u[p] = (a2 >> 16) | b2;
        float s0 = q0 - __uint_as_float(a2);
        float s1 = q1 - __uint_as_float(b2);
        r3.u[p] = (__float_as_uint(s0) >> 16) | (__float_as_uint(s1) & 0xFFFF0000u);
    }
    o1 = r1.v; o2 = r2.v; o3 = r3.v;
}

__device__ __forceinline__ s16x8 ld_frag(const unsigned int* p) {
    union { uint4 q; s16x8 v; } u;
    u.q = *(const uint4*)p;
    return u.v;
}

// ---- prep ----
// blocks 0..15: W -> fragment-order bf16 planes (unchanged layout):
//   group g = ks*4 + ct, 768 u32/group: {p1[64 lanes x 4u32], p2[...], p3[...]}
// block 16: e_norm -> fragment-order bf16 planes for the stage-2 MFMA B:
//   group ge = k2*4 + ce (8 groups x 768 u32 at WS_EN); lane l of (ge,plane)
//   holds en[e = ce*16 + (l&15)][d = k2*32 + (l>>4)*8 .. +8).
__global__ void prep(const float* __restrict__ W, const float* __restrict__ E,
                     unsigned int* __restrict__ ws) {
    const int tid = threadIdx.x;
    if (blockIdx.x < 16) {
        const int idx = blockIdx.x * 256 + tid;     // chunk: row*64 + k8
        const int row = idx >> 6, k8 = idx & 63;
        const float* src = W + (size_t)row * KD + k8 * 8;
        float4 lo = *(const float4*)src, hi = *(const float4*)(src + 4);
        s16x8 o1, o2, o3;
        split8(lo, hi, o1, o2, o3);
        union { s16x8 v; uint4 q; } u1, u2, u3;
        u1.v = o1; u2.v = o2; u3.v = o3;
        const int ks = k8 >> 2, lk = k8 & 3, ct = row >> 4, lr = row & 15;
        const int g = ks * 4 + ct, lane = lk * 16 + lr;
        unsigned int* base = ws + (size_t)g * 768 + lane * 4;
        *(uint4*)(base)       = u1.q;
        *(uint4*)(base + 256) = u2.q;
        *(uint4*)(base + 512) = u3.q;
    } else {
        const int er = tid >> 2, part = tid & 3;    // expert row, d-quarter
        float ss = 0.f;
        float4 ev[4];
        #pragma unroll
        for (int u = 0; u < 4; ++u) {
            ev[u] = *(const float4*)(E + er * DE + part * 16 + u * 4);
            ss = fmaf(ev[u].x, ev[u].x, ss);
            ss = fmaf(ev[u].y, ev[u].y, ss);
            ss = fmaf(ev[u].z, ev[u].z, ss);
            ss = fmaf(ev[u].w, ev[u].w, ss);
        }
        ss += __shfl_xor(ss, 1, 64);
        ss += __shfl_xor(ss, 2, 64);
        const float inv_e = 1.0f / fmaxf(sqrtf(ss), 1e-12f);
        #pragma unroll
        for (int u = 0; u < 4; ++u) {
            ev[u].x *= inv_e; ev[u].y *= inv_e; ev[u].z *= inv_e; ev[u].w *= inv_e;
        }
        #pragma unroll
        for (int half = 0; half < 2; ++half) {      // 8 consecutive d each
            const int d0 = part * 16 + half * 8;
            s16x8 o1, o2, o3;
            split8(ev[half * 2], ev[half * 2 + 1], o1, o2, o3);
            union { s16x8 v; uint4 q; } u1, u2, u3;
            u1.v = o1; u2.v = o2; u3.v = o3;
            const int k2 = d0 >> 5, kg = (d0 >> 3) & 3;
            const int ge = k2 * 4 + (er >> 4), l = (er & 15) | (kg << 4);
            unsigned int* base = ws + WS_EN + (size_t)ge * 768 + l * 4;
            *(uint4*)(base)       = u1.q;
            *(uint4*)(base + 256) = u2.q;
            *(uint4*)(base + 512) = u3.q;
        }
    }
}

// ---- fused main ----
// Stage-1 (round-7 structure, best measured): A per-wave LDS slice via
// global_load_lds; B 12KB/step staged once per block, double-buffered; one
// vmcnt(0)+s_barrier per step. Stage-2 now MFMA too: h_norm stored [tok][d]
// (stride 68) so A-fragments are contiguous b128 reads; e_norm-split B frags
// from workspace (24KB, L1-hot). Each wave consumes only its own 32 tokens
// after the scatter -> no second __syncthreads; epilogue runs on the
// C-fragment layout (e = ce*16 + lane&15, tokens = wv*32+rt*16+lk*4+reg).
// LDS: [0,6144) B dbuf | [6144,10240) A slices; h_norm overlay [0,8704).
__global__ __launch_bounds__(256, 4) void moe_all(const float* __restrict__ h,
                                                  const unsigned int* __restrict__ wsW,
                                                  const float* __restrict__ tau_p,
                                                  float* __restrict__ out) {
    __shared__ float smem[10240];

    const int tid = threadIdx.x;
    const int lane = tid & 63;
    const int wv = tid >> 6;          // wave 0..3 -> tokens [wv*32, wv*32+32)
    const int lr = lane & 15;         // fragment row/col within 16
    const int lk = lane >> 4;         // k-group 0..3
    const long tok0 = (long)blockIdx.x * BM;

    f32x4 acc[2][4];                  // stage-1 [row-tile][col-tile]
    #pragma unroll
    for (int rt = 0; rt < 2; ++rt)
        #pragma unroll
        for (int ct = 0; ct < 4; ++ct)
            acc[rt][ct] = (f32x4){0.f, 0.f, 0.f, 0.f};

#define STAGE_A(KS)                                                            \
    {                                                                          \
        _Pragma("unroll")                                                      \
        for (int n = 0; n < 4; ++n) {                                          \
            const int flat = (wv * 4 + n) * 64 + lane;                         \
            const int t = flat >> 3, q = flat & 7;                             \
            const int qs = q ^ (t & 7);                                        \
            const float* g = h + (tok0 + t) * (long)KD + (KS) * 32 + qs * 4;   \
            float* l = smem + 6144 + wv * 1024 + n * 256;                      \
            __builtin_amdgcn_global_load_lds((gp1_t)(const void*)g,            \
                                             (lp3_t)(void*)l, 16, 0, 0);       \
        }                                                                      \
    }

#define STAGE_B(CUR, KS)                                                       \
    {                                                                          \
        _Pragma("unroll")                                                      \
        for (int i = 0; i < 3; ++i) {                                          \
            const unsigned int* g = wsW + (size_t)(KS) * 3072 + i * 1024       \
                                    + wv * 256 + lane * 4;                     \
            float* l = smem + (CUR) * 3072 + i * 1024 + wv * 256;              \
            __builtin_amdgcn_global_load_lds((gp1_t)(const void*)g,            \
                                             (lp3_t)(void*)l, 16, 0, 0);       \
        }                                                                      \
    }

    STAGE_B(0, 0);
    STAGE_A(0);

    const int sw = lr & 7;
    const int q0 = (lk * 2) ^ sw;
    const int q1 = (lk * 2 + 1) ^ sw;
    const float* abase = smem + 6144 + wv * 1024;

    for (int ks = 0; ks < NS; ++ks) {
        const int cur = ks & 1;
        asm volatile("s_waitcnt vmcnt(0)" ::: "memory");
        __builtin_amdgcn_s_barrier();
        if (ks + 1 < NS) { STAGE_B(cur ^ 1, ks + 1); }
        __builtin_amdgcn_sched_barrier(0);

        float4 xl0 = *(const float4*)(abase + lr * 32 + q0 * 4);
        float4 xh0 = *(const float4*)(abase + lr * 32 + q1 * 4);
        float4 xl1 = *(const float4*)(abase + (lr + 16) * 32 + q0 * 4);
        float4 xh1 = *(const float4*)(abase + (lr + 16) * 32 + q1 * 4);
        asm volatile("s_waitcnt lgkmcnt(0)" ::: "memory");
        if (ks + 1 < NS) { STAGE_A(ks + 1); }
        __builtin_amdgcn_sched_barrier(0);

        s16x8 a1[2], a2[2], a3[2];
        split8(xl0, xh0, a1[0], a2[0], a3[0]);
        split8(xl1, xh1, a1[1], a2[1], a3[1]);

        #pragma unroll
        for (int ct = 0; ct < 4; ++ct) {
            const unsigned int* bb =
                (const unsigned int*)(smem + cur * 3072 + ct * 768) + lane * 4;
            s16x8 b1 = ld_frag(bb);
            s16x8 b2 = ld_frag(bb + 256);
            s16x8 b3 = ld_frag(bb + 512);
            f32x4 c0 = acc[0][ct], c1 = acc[1][ct];
            c0 = __builtin_amdgcn_mfma_f32_16x16x32_bf16(a1[0], b1, c0, 0, 0, 0);
            c1 = __builtin_amdgcn_mfma_f32_16x16x32_bf16(a1[1], b1, c1, 0, 0, 0);
            c0 = __builtin_amdgcn_mfma_f32_16x16x32_bf16(a2[0], b1, c0, 0, 0, 0);
            c1 = __builtin_amdgcn_mfma_f32_16x16x32_bf16(a2[1], b1, c1, 0, 0, 0);
            c0 = __builtin_amdgcn_mfma_f32_16x16x32_bf16(a1[0], b2, c0, 0, 0, 0);
            c1 = __builtin_amdgcn_mfma_f32_16x16x32_bf16(a1[1], b2, c1, 0, 0, 0);
            c0 = __builtin_amdgcn_mfma_f32_16x16x32_bf16(a3[0], b1, c0, 0, 0, 0);
            c1 = __builtin_amdgcn_mfma_f32_16x16x32_bf16(a3[1], b1, c1, 0, 0, 0);
            c0 = __builtin_amdgcn_mfma_f32_16x16x32_bf16(a2[0], b2, c0, 0, 0, 0);
            c1 = __builtin_amdgcn_mfma_f32_16x16x32_bf16(a2[1], b2, c1, 0, 0, 0);
            c0 = __builtin_amdgcn_mfma_f32_16x16x32_bf16(a1[0], b3, c0, 0, 0, 0);
            c1 = __builtin_amdgcn_mfma_f32_16x16x32_bf16(a1[1], b3, c1, 0, 0, 0);
            acc[0][ct] = c0; acc[1][ct] = c1;
        }
    }

    // ---- per-token L2 norm from fragments ----
    // C/D layout: col = lane&15 (d), row = (lane>>4)*4 + reg (token within 16)
    float inv_n[2][4];
    #pragma unroll
    for (int rt = 0; rt < 2; ++rt) {
        #pragma unroll
        for (int r = 0; r < 4; ++r) {
            float ss = 0.f;
            #pragma unroll
            for (int ct = 0; ct < 4; ++ct)
                ss = fmaf(acc[rt][ct][r], acc[rt][ct][r], ss);
            ss += __shfl_xor(ss, 1, 64);
            ss += __shfl_xor(ss, 2, 64);
            ss += __shfl_xor(ss, 4, 64);
            ss += __shfl_xor(ss, 8, 64);
            inv_n[rt][r] = 1.0f / fmaxf(sqrtf(ss), 1e-12f);
        }
    }

    __syncthreads();   // all waves done with staging LDS (h_norm overlays it)

    // h_norm -> smem as [tok][d], stride 68 (2-way banks on scatter: free).
    // Each wave writes and later reads ONLY its own 32 tokens -> no 2nd sync.
    #pragma unroll
    for (int rt = 0; rt < 2; ++rt)
        #pragma unroll
        for (int ct = 0; ct < 4; ++ct)
            #pragma unroll
            for (int r = 0; r < 4; ++r) {
                const int t = wv * 32 + rt * 16 + lk * 4 + r;
                smem[t * LD2 + ct * 16 + lr] = acc[rt][ct][r] * inv_n[rt][r];
            }

    // ---- stage 2 (MFMA): scores[32][64] per wave = h_norm @ e_norm^T ----
    const unsigned int* wsE = wsW + WS_EN;
    f32x4 sc[2][4];                    // [rt][e-tile]
    #pragma unroll
    for (int rt = 0; rt < 2; ++rt)
        #pragma unroll
        for (int ce = 0; ce < 4; ++ce)
            sc[rt][ce] = (f32x4){0.f, 0.f, 0.f, 0.f};

    #pragma unroll
    for (int k2 = 0; k2 < 2; ++k2) {
        s16x8 ha1[2], ha2[2], ha3[2];
        #pragma unroll
        for (int rt = 0; rt < 2; ++rt) {
            const float* ra = smem + (wv * 32 + rt * 16 + lr) * LD2 + k2 * 32 + lk * 8;
            float4 lo = *(const float4*)ra;
            float4 hi = *(const float4*)(ra + 4);
            split8(lo, hi, ha1[rt], ha2[rt], ha3[rt]);
        }
        #pragma unroll
        for (int ce = 0; ce < 4; ++ce) {
            const unsigned int* bb = wsE + (k2 * 4 + ce) * 768 + lane * 4;
            s16x8 b1 = ld_frag(bb);
            s16x8 b2 = ld_frag(bb + 256);
            s16x8 b3 = ld_frag(bb + 512);
            #pragma unroll
            for (int rt = 0; rt < 2; ++rt) {
                f32x4 c = sc[rt][ce];
                c = __builtin_amdgcn_mfma_f32_16x16x32_bf16(ha1[rt], b1, c, 0, 0, 0);
                c = __builtin_amdgcn_mfma_f32_16x16x32_bf16(ha2[rt], b1, c, 0, 0, 0);
                c = __builtin_amdgcn_mfma_f32_16x16x32_bf16(ha1[rt], b2, c, 0, 0, 0);
                c = __builtin_amdgcn_mfma_f32_16x16x32_bf16(ha3[rt], b1, c, 0, 0, 0);
                c = __builtin_amdgcn_mfma_f32_16x16x32_bf16(ha2[rt], b2, c, 0, 0, 0);
                c = __builtin_amdgcn_mfma_f32_16x16x32_bf16(ha1[rt], b3, c, 0, 0, 0);
                sc[rt][ce] = c;
            }
        }
    }

    // ---- epilogue on C-fragment layout ----
    // Lane holds, for token = wv*32 + rt*16 + lk*4 + reg, experts e = ce*16+lr.
    // 16-lane group (fixed lk) spans all 64 experts -> same shuffle reductions.
    const float inv_tau = 1.0f / tau_p[0];
    float* outS = out;                        // sparse_gates [NT][64]
    float* outI = out + (size_t)NT * 64;      // topk_indices [NT][2] (as float)
    float* outF = out + (size_t)NT * 66;      // full_gates   [NT][64]

    #pragma unroll
    for (int rt = 0; rt < 2; ++rt) {
        #pragma unroll
        for (int r = 0; r < 4; ++r) {
            const long tok = tok0 + wv * 32 + rt * 16 + lk * 4 + r;
            float s[4];
            #pragma unroll
            for (int ce = 0; ce < 4; ++ce) s[ce] = sc[rt][ce][r] * inv_tau;

            float m = fmaxf(fmaxf(s[0], s[1]), fmaxf(s[2], s[3]));
            m = fmaxf(m, __shfl_xor(m, 1, 64));
            m = fmaxf(m, __shfl_xor(m, 2, 64));
            m = fmaxf(m, __shfl_xor(m, 4, 64));
            m = fmaxf(m, __shfl_xor(m, 8, 64));

            float g[4], z = 0.f;
            #pragma unroll
            for (int ce = 0; ce < 4; ++ce) { g[ce] = __expf(s[ce] - m); z += g[ce]; }
            z += __shfl_xor(z, 1, 64);
            z += __shfl_xor(z, 2, 64);
            z += __shfl_xor(z, 4, 64);
            z += __shfl_xor(z, 8, 64);
            const float invZ = 1.0f / z;

            #pragma unroll
            for (int ce = 0; ce < 4; ++ce)
                outF[tok * 64 + ce * 16 + lr] = g[ce] * invZ;   // 64B/16-lane coalesced

            // top-2 on s (monotone with gates); ties -> lower index (jax top_k)
            float v1 = -3.4e38f, v2 = -3.4e38f;
            int i1 = 1 << 20, i2 = 1 << 20;
            #pragma unroll
            for (int ce = 0; ce < 4; ++ce) {
                float v = s[ce];
                int e = ce * 16 + lr;
                if (v > v1 || (v == v1 && e < i1)) { v2 = v1; i2 = i1; v1 = v; i1 = e; }
                else if (v > v2 || (v == v2 && e < i2)) { v2 = v; i2 = e; }
            }
            #pragma unroll
            for (int msk = 1; msk <= 8; msk <<= 1) {
                float o1 = __shfl_xor(v1, msk, 64); int oi1 = __shfl_xor(i1, msk, 64);
                float o2 = __shfl_xor(v2, msk, 64); int oi2 = __shfl_xor(i2, msk, 64);
                if (o1 > v1 || (o1 == v1 && oi1 < i1)) {
                    if (v1 > o2 || (v1 == o2 && i1 < oi2)) { v2 = v1; i2 = i1; }
                    else { v2 = o2; i2 = oi2; }
                    v1 = o1; i1 = oi1;
                } else {
                    if (o1 > v2 || (o1 == v2 && oi1 < i2)) { v2 = o1; i2 = oi1; }
                }
            }

            // softmax over the two top GATE values
            float gv1 = __expf(v1 - m) * invZ;
            float gv2 = __expf(v2 - m) * invZ;
            float qq = __expf(gv2 - gv1);
            float w1 = 1.0f / (1.0f + qq);
            float w2 = qq * w1;

            #pragma unroll
            for (int ce = 0; ce < 4; ++ce) {
                int e = ce * 16 + lr;
                outS[tok * 64 + e] = (e == i1) ? w1 : ((e == i2) ? w2 : 0.0f);
            }
            if (lr == 0) {
                *(float2*)(outI + tok * 2) = make_float2((float)i1, (float)i2);
            }
        }
    }
#undef STAGE_A
#undef STAGE_B
}

extern "C" void kernel_launch(void* const* d_in, const int* in_sizes, int n_in,
                              void* d_out, int out_size, void* d_ws, size_t ws_size,
                              hipStream_t stream) {
    const float* h   = (const float*)d_in[0];
    const float* W   = (const float*)d_in[1];
    const float* E   = (const float*)d_in[2];
    const float* tau = (const float*)d_in[3];
    float* out = (float*)d_out;
    unsigned int* ws = (unsigned int*)d_ws;   // 192KB W frags + 24KB e_norm frags

    prep<<<17, 256, 0, stream>>>(W, E, ws);
    moe_all<<<NT / BM, 256, 0, stream>>>(h, ws, tau, out);
}